// Round 7
// baseline (439.519 us; speedup 1.0000x reference)
//
#include <hip/hip_runtime.h>

typedef unsigned short u16;
typedef unsigned int u32;
typedef __bf16 bf16;
typedef __attribute__((ext_vector_type(8))) __bf16 bf16x8;
typedef __attribute__((ext_vector_type(4))) float f32x4;
typedef __attribute__((ext_vector_type(8))) float f32x8;
typedef __attribute__((ext_vector_type(4))) u16 u16x4;

#define NKPT 80
#define LSPIRAL 41

__device__ __forceinline__ float b2f(u16 v) { return __uint_as_float(((u32)v) << 16); }
__device__ __forceinline__ u16 f2b(float f) {
  u32 u = __float_as_uint(f);
  return (u16)((u + 0x7FFFu + ((u >> 16) & 1u)) >> 16);
}

__device__ __forceinline__ void gload_lds16(const u16* g, u16* l) {
  __builtin_amdgcn_global_load_lds(
      (const __attribute__((address_space(1))) unsigned int*)g,
      (__attribute__((address_space(3))) unsigned int*)l,
      16, 0, 0);
}

__global__ __launch_bounds__(256)
void cvt_f2b(const float* __restrict__ src, u16* __restrict__ dst, int n4) {
  const int i = blockIdx.x * 256 + threadIdx.x;
  if (i >= n4) return;
  const f32x4 v = *(const f32x4*)(src + i * 4);
  u16x4 o;
#pragma unroll
  for (int t = 0; t < 4; t++) o[t] = f2b(v[t]);
  *(u16x4*)(dst + i * 4) = o;
}

__global__ __launch_bounds__(256)
void zero_f32(float* __restrict__ p, int n4) {
  const int i = blockIdx.x * 256 + threadIdx.x;
  if (i < n4) ((f32x4*)p)[i] = (f32x4){0.f, 0.f, 0.f, 0.f};
}

// NT GEMM, MFMA 16x16x32 bf16, BK=64, 256 threads (4 waves, 2x2 wave grid).
// XOR chunk swizzle: global chunk c of row r lives at LDS slot c^(r&7)
// (staging permutes WHICH chunk a lane fetches, since the LDS-DMA slot is
// HW-fixed at base+lane*16). Fragment reads use slot (kk*4+quad)^(lane&7):
// 16 lanes -> 8 distinct slots -> 2-way bank aliasing = free (m136).
// GATHER=1: A is (128*80, C), C=1<<LOG2C; row r=b*80+n reads
//   A[(b*80+idx[n, k>>LOG2C])*C + (k&(C-1))]. Only the split's l-window
//   (LW entries) of idx is staged in LDS.
// BCVT=1: B is fp32, converted in registers while staging.
// OUTM=0: direct bf16 out + bias(+ELU).  OUTM=1: atomicAdd fp32 P.
template <int BM, int BN, int GATHER, int LOG2C, int OUTM, int BCVT, int LW>
__global__ __launch_bounds__(256)
void gemm_sp(const u16* __restrict__ A, const void* __restrict__ Wt,
             const int* __restrict__ gidx, float* __restrict__ P,
             u16* __restrict__ Out, const float* __restrict__ bias, int act,
             int N, int K, int itersTotal, int itersPerSplit) {
  constexpr int BK = 64;
  constexpr int WN = BN / 2;
  constexpr int TN = WN / 16;
  constexpr int IA = BM / 32;
  constexpr int IB = BN / 32;
  constexpr int CMASK = (1 << LOG2C) - 1;

  __shared__ u16 As[BM * BK];
  __shared__ u16 Bs[BN * BK];
  __shared__ int idx_s[GATHER ? NKPT * LW : 1];

  const int tid = threadIdx.x;
  const int lane = tid & 63;
  const int wave = tid >> 6;

  const int bm0 = blockIdx.x * BM;
  const int bn0 = blockIdx.y * BN;
  const int split = blockIdx.z;
  const int it0 = split * itersPerSplit;
  const int itEnd = min(itersTotal, it0 + itersPerSplit);
  const int l0 = GATHER ? ((it0 * BK) >> LOG2C) : 0;

  if (GATHER) {  // stage only this split's spiral-index window
    for (int t = tid; t < NKPT * LW; t += 256) {
      const int n = t / LW;
      const int w = t - n * LW;
      idx_s[t] = gidx[n * LSPIRAL + min(l0 + w, LSPIRAL - 1)];
    }
  }

  // Wave-chunk q = 8 rows x 64 k (1024 B). Lane = rIn*8 + cl handles row rIn;
  // it FETCHES global chunk (cl ^ rIn); DMA stores at chunkBase + lane*16.
  const int rIn = lane >> 3;
  const int koff = ((lane & 7) ^ rIn) * 8;

  int aBase[IA];
  const int* aIdxP[IA];
  const u16* aPtr[IA];
  u16* aDst[IA];
#pragma unroll
  for (int i = 0; i < IA; i++) {
    const int q = i * 4 + wave;
    const int r = bm0 + q * 8 + rIn;
    aDst[i] = As + q * 512;
    if (GATHER) {
      const int b = (r * 52429) >> 22;  // r/80 exact for r<10240
      const int n = r - b * 80;
      aBase[i] = (b * NKPT) << LOG2C;
      aIdxP[i] = idx_s + n * LW;
    } else {
      aPtr[i] = A + (size_t)r * K + koff;
    }
  }
  const u16* bPtrH[IB];
  const float* bPtrF[IB];
  u16* bDst[IB];
#pragma unroll
  for (int i = 0; i < IB; i++) {
    const int q = i * 4 + wave;
    const int o = bn0 + q * 8 + rIn;
    bDst[i] = Bs + q * 512;
    if (BCVT) bPtrF[i] = (const float*)Wt + (size_t)o * K + koff;
    else bPtrH[i] = (const u16*)Wt + (size_t)o * K + koff;
  }

  f32x4 acc[4][TN];
#pragma unroll
  for (int i = 0; i < 4; i++)
#pragma unroll
    for (int j = 0; j < TN; j++) acc[i][j] = (f32x4){0.f, 0.f, 0.f, 0.f};

  const int wm = (wave >> 1) * 64;
  const int wn = (wave & 1) * WN;
  const int m15 = lane & 15;
  const int quad = lane >> 4;
  // fragment slots (undo swizzle): desired chunk kk*4+quad, row&7 == lane&7
  const int fko0 = ((0 + quad) ^ (lane & 7)) * 8;
  const int fko1 = ((4 + quad) ^ (lane & 7)) * 8;

  __syncthreads();  // idx_s ready

  for (int it = it0; it < itEnd; ++it) {
    const int k0 = it * BK;

    bf16x8 bw[IB];
    if (BCVT) {
#pragma unroll
      for (int i = 0; i < IB; i++) {
        const f32x8 v = *(const f32x8*)(bPtrF[i] + k0);
#pragma unroll
        for (int t = 0; t < 8; t++) bw[i][t] = (bf16)v[t];
      }
    }

    if (GATHER) {
      const int dl = (k0 >> LOG2C) - l0;    // tile-uniform spiral position
      const int cb = (k0 & CMASK) + koff;
#pragma unroll
      for (int i = 0; i < IA; i++) {
        int J = aIdxP[i][dl];
        J = min(max(J, 0), NKPT - 1);
        gload_lds16(A + aBase[i] + (J << LOG2C) + cb, aDst[i]);
      }
    } else {
#pragma unroll
      for (int i = 0; i < IA; i++) gload_lds16(aPtr[i] + k0, aDst[i]);
    }
    if (BCVT) {
#pragma unroll
      for (int i = 0; i < IB; i++) *(bf16x8*)(bDst[i] + lane * 8) = bw[i];
    } else {
#pragma unroll
      for (int i = 0; i < IB; i++) gload_lds16(bPtrH[i] + k0, bDst[i]);
    }

    __syncthreads();

#pragma unroll
    for (int kk = 0; kk < 2; kk++) {
      const int fko = kk ? fko1 : fko0;
      bf16x8 av[4], bv[TN];
#pragma unroll
      for (int i = 0; i < 4; i++)
        av[i] = *(const bf16x8*)(As + (wm + i * 16 + m15) * BK + fko);
#pragma unroll
      for (int j = 0; j < TN; j++)
        bv[j] = *(const bf16x8*)(Bs + (wn + j * 16 + m15) * BK + fko);
#pragma unroll
      for (int i = 0; i < 4; i++)
#pragma unroll
        for (int j = 0; j < TN; j++)
          acc[i][j] = __builtin_amdgcn_mfma_f32_16x16x32_bf16(av[i], bv[j], acc[i][j], 0, 0, 0);
    }
    __syncthreads();
  }

  // C/D layout: col = lane&15, row = quad*4 + reg  (m89/m91)
#pragma unroll
  for (int i = 0; i < 4; i++) {
    const int r = bm0 + wm + i * 16 + quad * 4;
#pragma unroll
    for (int j = 0; j < TN; j++) {
      const int c = bn0 + wn + j * 16 + m15;
      if (OUTM == 0) {
        const float bv = bias[c];
#pragma unroll
        for (int t = 0; t < 4; t++) {
          float v = acc[i][j][t] + bv;
          if (act) v = v > 0.f ? v : (__expf(v) - 1.f);
          Out[(size_t)(r + t) * N + c] = f2b(v);
        }
      } else {
#pragma unroll
        for (int t = 0; t < 4; t++)
          atomicAdd(P + (size_t)(r + t) * N + c, acc[i][j][t]);
      }
    }
  }
}

__global__ __launch_bounds__(256)
void epilogue_k(const float* __restrict__ P, const float* __restrict__ bias,
                u16* __restrict__ out, int MN, int N, int act) {
  const int i4 = (blockIdx.x * 256 + threadIdx.x) * 4;
  if (i4 >= MN) return;
  const f32x4 acc = *(const f32x4*)(P + i4);
  const int col = i4 % N;
  u16x4 o;
#pragma unroll
  for (int t = 0; t < 4; t++) {
    float v = acc[t] + bias[col + t];
    if (act) v = v > 0.f ? v : (__expf(v) - 1.f);
    o[t] = f2b(v);
  }
  *(u16x4*)(out + i4) = o;
}

__global__ __launch_bounds__(256)
void final_k(const u16* __restrict__ h3, const float* __restrict__ W4,
             const float* __restrict__ b4, const int* __restrict__ gidx,
             float* __restrict__ out) {
  const int lane = threadIdx.x & 63;
  const int wave = threadIdx.x >> 6;
  const int r = blockIdx.x * 4 + wave;  // < 10240
  const int b = r / 80;
  const int n = r - b * 80;
  const int* ip = gidx + n * LSPIRAL;
  const float* w0 = W4 + lane;
  const float* w1 = W4 + 2624 + lane;
  const u16* hb = h3 + b * (NKPT * 64) + lane;
  float a0 = 0.f, a1 = 0.f;
  for (int l = 0; l < LSPIRAL; l++) {
    int J = ip[l];
    J = min(max(J, 0), NKPT - 1);
    const float hv = b2f(hb[J * 64]);
    a0 += hv * w0[l * 64];
    a1 += hv * w1[l * 64];
  }
#pragma unroll
  for (int off = 32; off > 0; off >>= 1) {
    a0 += __shfl_down(a0, off, 64);
    a1 += __shfl_down(a1, off, 64);
  }
  if (lane == 0) {
    out[r * 2 + 0] = a0 + b4[0];
    out[r * 2 + 1] = a1 + b4[1];
  }
}

extern "C" void kernel_launch(void* const* d_in, const int* in_sizes, int n_in,
                              void* d_out, int out_size, void* d_ws, size_t ws_size,
                              hipStream_t stream) {
  const float* x  = (const float*)d_in[0];
  const float* W0 = (const float*)d_in[1];
  const float* b0 = (const float*)d_in[2];
  const float* W1 = (const float*)d_in[3];
  const float* b1 = (const float*)d_in[4];
  const float* W2 = (const float*)d_in[5];
  const float* b2 = (const float*)d_in[6];
  const float* W3 = (const float*)d_in[7];
  const float* b3 = (const float*)d_in[8];
  const float* W4 = (const float*)d_in[9];
  const float* b4 = (const float*)d_in[10];
  const int* idx = (const int*)d_in[11];
  float* out = (float*)d_out;

  char* ws = (char*)d_ws;
  u16* hA  = (u16*)(ws);                  // 5,242,880 B  (h0, then h2)
  u16* hB  = (u16*)(ws + 5242880);        // 5,242,880 B  (h1, then h3)
  u16* xb  = (u16*)(ws + 10485760);       //   262,144 B
  u16* W1b = (u16*)(ws + 10747904);       // 5,373,952 B
  u16* W2b = (u16*)(ws + 16121856);       // 2,686,976 B
  u16* W3b = (u16*)(ws + 18808832);       //   671,744 B
  float* P = (float*)(ws + 19480576);     // 10,485,760 B -> end 29,966,336

  const bool full = ws_size >= (size_t)29966336;

  if (full) {
    cvt_f2b<<<128, 256, 0, stream>>>(x, xb, 32768);
    cvt_f2b<<<2624, 256, 0, stream>>>(W1, W1b, 671744);
    cvt_f2b<<<1312, 256, 0, stream>>>(W2, W2b, 335872);
    cvt_f2b<<<328, 256, 0, stream>>>(W3, W3b, 83968);

    // L0: M=128 N=20480 K=1024, fp32 B cvt in staging, split 2 -> 640 blocks
    zero_f32<<<2560, 256, 0, stream>>>(P, 655360);
    gemm_sp<128, 64, 0, 0, 1, 1, 1><<<dim3(1, 320, 2), 256, 0, stream>>>(
        xb, W0, idx, P, nullptr, nullptr, 0, 20480, 1024, 16, 8);
    epilogue_k<<<2560, 256, 0, stream>>>(P, b0, hA, 2621440, 20480, 0);

    // L1: M=10240 N=256 K=10496, split 6 -> 960 blocks (3.75/CU)
    zero_f32<<<2560, 256, 0, stream>>>(P, 655360);
    gemm_sp<128, 128, 1, 8, 1, 0, 16><<<dim3(80, 2, 6), 256, 0, stream>>>(
        hA, W1b, idx, P, nullptr, nullptr, 0, 256, 10496, 164, 28);
    epilogue_k<<<2560, 256, 0, stream>>>(P, b1, hB, 2621440, 256, 1);

    // L2: N=128 K=10496, split 10 -> 800 blocks (3.1/CU)
    zero_f32<<<1280, 256, 0, stream>>>(P, 327680);
    gemm_sp<128, 128, 1, 8, 1, 0, 16><<<dim3(80, 1, 10), 256, 0, stream>>>(
        hB, W2b, idx, P, nullptr, nullptr, 0, 128, 10496, 164, 17);
    epilogue_k<<<1280, 256, 0, stream>>>(P, b2, hA, 1310720, 128, 1);

    // L3: N=64 K=5248, split 12 -> 960 blocks
    zero_f32<<<640, 256, 0, stream>>>(P, 163840);
    gemm_sp<128, 64, 1, 7, 1, 0, 16><<<dim3(80, 1, 12), 256, 0, stream>>>(
        hA, W3b, idx, P, nullptr, nullptr, 0, 64, 5248, 82, 7);
    epilogue_k<<<640, 256, 0, stream>>>(P, b3, hB, 655360, 64, 1);
  } else {
    // Fallback (<= 10.5 MB ws): in-staging weight cvt, no split-K
    cvt_f2b<<<128, 256, 0, stream>>>(x, hB, 32768);
    gemm_sp<128, 64, 0, 0, 0, 1, 1><<<dim3(1, 320, 1), 256, 0, stream>>>(
        hB, W0, idx, nullptr, hA, b0, 0, 20480, 1024, 16, 16);
    gemm_sp<128, 128, 1, 8, 0, 1, 44><<<dim3(80, 2, 1), 256, 0, stream>>>(
        hA, W1, idx, nullptr, hB, b1, 1, 256, 10496, 164, 164);
    gemm_sp<128, 128, 1, 8, 0, 1, 44><<<dim3(80, 1, 1), 256, 0, stream>>>(
        hB, W2, idx, nullptr, hA, b2, 1, 128, 10496, 164, 164);
    gemm_sp<128, 64, 1, 7, 0, 1, 44><<<dim3(80, 1, 1), 256, 0, stream>>>(
        hA, W3, idx, nullptr, hB, b3, 1, 64, 5248, 82, 82);
  }

  final_k<<<2560, 256, 0, stream>>>(hB, W4, b4, idx, out);
}

// Round 8
// 369.496 us; speedup vs baseline: 1.1895x; 1.1895x over previous
//
#include <hip/hip_runtime.h>

typedef unsigned short u16;
typedef unsigned int u32;
typedef __bf16 bf16;
typedef __attribute__((ext_vector_type(8))) __bf16 bf16x8;
typedef __attribute__((ext_vector_type(4))) float f32x4;
typedef __attribute__((ext_vector_type(8))) float f32x8;
typedef __attribute__((ext_vector_type(4))) u16 u16x4;

#define NKPT 80
#define LSPIRAL 41

__device__ __forceinline__ float b2f(u16 v) { return __uint_as_float(((u32)v) << 16); }
__device__ __forceinline__ u16 f2b(float f) {
  u32 u = __float_as_uint(f);
  return (u16)((u + 0x7FFFu + ((u >> 16) & 1u)) >> 16);
}

// One fused conversion pass: x, W1, W2, W3 -> bf16 (segment by flat f32x4 id)
__global__ __launch_bounds__(256)
void cvt_all(const float* __restrict__ x, const float* __restrict__ W1,
             const float* __restrict__ W2, const float* __restrict__ W3,
             u16* __restrict__ xb, u16* __restrict__ W1b,
             u16* __restrict__ W2b, u16* __restrict__ W3b) {
  const int i = blockIdx.x * 256 + threadIdx.x;  // f32x4 index
  const float* src; u16* dst; int off;
  if (i < 32768)        { src = x;  dst = xb;  off = 0; }
  else if (i < 704512)  { src = W1; dst = W1b; off = 32768; }
  else if (i < 1040384) { src = W2; dst = W2b; off = 704512; }
  else if (i < 1124352) { src = W3; dst = W3b; off = 1040384; }
  else return;
  const int j = i - off;
  const f32x4 v = *(const f32x4*)(src + (size_t)j * 4);
  u16x4 o;
#pragma unroll
  for (int t = 0; t < 4; t++) o[t] = f2b(v[t]);
  *(u16x4*)(dst + (size_t)j * 4) = o;
}

__global__ __launch_bounds__(256)
void zero_f32(float* __restrict__ p, int n4) {
  const int i = blockIdx.x * 256 + threadIdx.x;
  if (i < n4) ((f32x4*)p)[i] = (f32x4){0.f, 0.f, 0.f, 0.f};
}

// NT GEMM, MFMA 16x16x32 bf16, BK=64, 256 threads (4 waves, 2x2 wave grid).
// SOFTWARE-PIPELINED K-loop (depth-1 register prefetch): iter k+1's global
// loads issue before iter k's MFMA phase; the vmcnt wait lands at the
// ds_write one full iteration later -> staging latency hidden under MFMA.
// XOR chunk swizzle: global chunk c of row r lives at LDS slot c^(r&7);
// fragment reads use slot (kk*4+quad)^(lane&7) -> 2-way bank alias = free.
// GATHER=1: A is (128*80, C), C=1<<LOG2C; row r=b*80+n reads
//   A[(b*80+idx[n, k>>LOG2C])*C + (k&(C-1))]; split's l-window in idx_s.
// BCVT=1: B is fp32, converted at store time.
// OUTM=0: direct bf16 out + bias(+ELU).  OUTM=1: atomicAdd fp32 P.
template <int BM, int BN, int GATHER, int LOG2C, int OUTM, int BCVT, int LW>
__global__ __launch_bounds__(256)
void gemm_sp(const u16* __restrict__ A, const void* __restrict__ Wt,
             const int* __restrict__ gidx, float* __restrict__ P,
             u16* __restrict__ Out, const float* __restrict__ bias, int act,
             int N, int K, int itersTotal, int itersPerSplit) {
  constexpr int BK = 64;
  constexpr int WN = BN / 2;
  constexpr int TN = WN / 16;
  constexpr int IA = BM / 32;
  constexpr int IB = BN / 32;
  constexpr int CMASK = (1 << LOG2C) - 1;

  __shared__ u16 As[BM * BK];
  __shared__ u16 Bs[BN * BK];
  __shared__ int idx_s[GATHER ? NKPT * LW : 1];

  const int tid = threadIdx.x;
  const int lane = tid & 63;
  const int wave = tid >> 6;

  const int bm0 = blockIdx.x * BM;
  const int bn0 = blockIdx.y * BN;
  const int split = blockIdx.z;
  const int it0 = split * itersPerSplit;
  const int itEnd = min(itersTotal, it0 + itersPerSplit);
  const int l0 = GATHER ? ((it0 * BK) >> LOG2C) : 0;

  if (GATHER) {
    for (int t = tid; t < NKPT * LW; t += 256) {
      const int n = t / LW;
      const int w = t - n * LW;
      idx_s[t] = gidx[n * LSPIRAL + min(l0 + w, LSPIRAL - 1)];
    }
  }

  // Lane (rIn, cl): fetches global chunk (cl ^ rIn) of row rIn; stores to LDS
  // slot cl (addr chunkBase + lane*16).
  const int rIn = lane >> 3;
  const int koff = ((lane & 7) ^ rIn) * 8;

  int aBase[IA];
  const int* aIdxP[IA];
  const u16* aPtr[IA];
  u16* aDst[IA];
#pragma unroll
  for (int i = 0; i < IA; i++) {
    const int q = i * 4 + wave;
    const int r = bm0 + q * 8 + rIn;
    aDst[i] = As + q * 512;
    if (GATHER) {
      const int b = (r * 52429) >> 22;  // r/80 exact for r<10240
      const int n = r - b * 80;
      aBase[i] = (b * NKPT) << LOG2C;
      aIdxP[i] = idx_s + n * LW;
    } else {
      aPtr[i] = A + (size_t)r * K + koff;
    }
  }
  const u16* bPtrH[IB];
  const float* bPtrF[IB];
  u16* bDst[IB];
#pragma unroll
  for (int i = 0; i < IB; i++) {
    const int q = i * 4 + wave;
    const int o = bn0 + q * 8 + rIn;
    bDst[i] = Bs + q * 512;
    if (BCVT) bPtrF[i] = (const float*)Wt + (size_t)o * K + koff;
    else bPtrH[i] = (const u16*)Wt + (size_t)o * K + koff;
  }

  f32x4 acc[4][TN];
#pragma unroll
  for (int i = 0; i < 4; i++)
#pragma unroll
    for (int j = 0; j < TN; j++) acc[i][j] = (f32x4){0.f, 0.f, 0.f, 0.f};

  const int wm = (wave >> 1) * 64;
  const int wn = (wave & 1) * WN;
  const int m15 = lane & 15;
  const int quad = lane >> 4;
  const int fko0 = ((0 + quad) ^ (lane & 7)) * 8;
  const int fko1 = ((4 + quad) ^ (lane & 7)) * 8;

  if (GATHER) __syncthreads();  // idx_s ready before prologue gather

  bf16x8 curA[IA], nxtA[IA];
  bf16x8 curB[IB], nxtB[IB];
  f32x8 curBF[BCVT ? IB : 1], nxtBF[BCVT ? IB : 1];

  auto loadA = [&](int it, bf16x8* dst) {
    const int k0 = it * BK;
    if (GATHER) {
      const int dl = (k0 >> LOG2C) - l0;
      const int cb = (k0 & CMASK) + koff;
#pragma unroll
      for (int i = 0; i < IA; i++) {
        int J = aIdxP[i][dl];
        J = min(max(J, 0), NKPT - 1);
        dst[i] = *(const bf16x8*)(A + aBase[i] + (J << LOG2C) + cb);
      }
    } else {
#pragma unroll
      for (int i = 0; i < IA; i++) dst[i] = *(const bf16x8*)(aPtr[i] + k0);
    }
  };
  auto loadBH = [&](int it, bf16x8* dst) {
    const int k0 = it * BK;
#pragma unroll
    for (int i = 0; i < IB; i++) dst[i] = *(const bf16x8*)(bPtrH[i] + k0);
  };
  auto loadBF = [&](int it, f32x8* dst) {
    const int k0 = it * BK;
#pragma unroll
    for (int i = 0; i < IB; i++) dst[i] = *(const f32x8*)(bPtrF[i] + k0);
  };

  // Prologue: tile it0 -> regs
  loadA(it0, curA);
  if (BCVT) loadBF(it0, curBF); else loadBH(it0, curB);

  for (int it = it0; it < itEnd; ++it) {
    __syncthreads();  // WAR: previous iter's LDS readers done

    // store cur tile (compiler waits vmcnt for cur here — had a full iter)
#pragma unroll
    for (int i = 0; i < IA; i++) *(bf16x8*)(aDst[i] + lane * 8) = curA[i];
    if (BCVT) {
#pragma unroll
      for (int i = 0; i < IB; i++) {
        bf16x8 w;
#pragma unroll
        for (int t = 0; t < 8; t++) w[t] = (bf16)curBF[i][t];
        *(bf16x8*)(bDst[i] + lane * 8) = w;
      }
    } else {
#pragma unroll
      for (int i = 0; i < IB; i++) *(bf16x8*)(bDst[i] + lane * 8) = curB[i];
    }

    __syncthreads();  // tiles visible

    const bool more = (it + 1 < itEnd);
    if (more) {  // prefetch next tile; latency covered by MFMA phase below
      loadA(it + 1, nxtA);
      if (BCVT) loadBF(it + 1, nxtBF); else loadBH(it + 1, nxtB);
    }

#pragma unroll
    for (int kk = 0; kk < 2; kk++) {
      const int fko = kk ? fko1 : fko0;
      bf16x8 av[4], bv[TN];
#pragma unroll
      for (int i = 0; i < 4; i++)
        av[i] = *(const bf16x8*)(As + (wm + i * 16 + m15) * BK + fko);
#pragma unroll
      for (int j = 0; j < TN; j++)
        bv[j] = *(const bf16x8*)(Bs + (wn + j * 16 + m15) * BK + fko);
#pragma unroll
      for (int i = 0; i < 4; i++)
#pragma unroll
        for (int j = 0; j < TN; j++)
          acc[i][j] = __builtin_amdgcn_mfma_f32_16x16x32_bf16(av[i], bv[j], acc[i][j], 0, 0, 0);
    }

    if (more) {
#pragma unroll
      for (int i = 0; i < IA; i++) curA[i] = nxtA[i];
      if (BCVT) {
#pragma unroll
        for (int i = 0; i < IB; i++) curBF[i] = nxtBF[i];
      } else {
#pragma unroll
        for (int i = 0; i < IB; i++) curB[i] = nxtB[i];
      }
    }
  }

  // C/D layout: col = lane&15, row = quad*4 + reg  (m89/m91)
#pragma unroll
  for (int i = 0; i < 4; i++) {
    const int r = bm0 + wm + i * 16 + quad * 4;
#pragma unroll
    for (int j = 0; j < TN; j++) {
      const int c = bn0 + wn + j * 16 + m15;
      if (OUTM == 0) {
        const float bv = bias[c];
#pragma unroll
        for (int t = 0; t < 4; t++) {
          float v = acc[i][j][t] + bv;
          if (act) v = v > 0.f ? v : (__expf(v) - 1.f);
          Out[(size_t)(r + t) * N + c] = f2b(v);
        }
      } else {
#pragma unroll
        for (int t = 0; t < 4; t++)
          atomicAdd(P + (size_t)(r + t) * N + c, acc[i][j][t]);
      }
    }
  }
}

// bias (+ELU) on accumulated fp32 P -> bf16; optionally re-zero P afterwards
// (each location touched by exactly one thread: read-then-zero is race-free).
__global__ __launch_bounds__(256)
void epilogue_k(float* P, const float* __restrict__ bias,
                u16* __restrict__ out, int MN, int N, int act, int zeroAfter) {
  const int i4 = (blockIdx.x * 256 + threadIdx.x) * 4;
  if (i4 >= MN) return;
  const f32x4 acc = *(const f32x4*)(P + i4);
  if (zeroAfter) *(f32x4*)(P + i4) = (f32x4){0.f, 0.f, 0.f, 0.f};
  const int col = i4 % N;
  u16x4 o;
#pragma unroll
  for (int t = 0; t < 4; t++) {
    float v = acc[t] + bias[col + t];
    if (act) v = v > 0.f ? v : (__expf(v) - 1.f);
    o[t] = f2b(v);
  }
  *(u16x4*)(out + i4) = o;
}

__global__ __launch_bounds__(256)
void final_k(const u16* __restrict__ h3, const float* __restrict__ W4,
             const float* __restrict__ b4, const int* __restrict__ gidx,
             float* __restrict__ out) {
  const int lane = threadIdx.x & 63;
  const int wave = threadIdx.x >> 6;
  const int r = blockIdx.x * 4 + wave;  // < 10240
  const int b = r / 80;
  const int n = r - b * 80;
  const int* ip = gidx + n * LSPIRAL;
  const float* w0 = W4 + lane;
  const float* w1 = W4 + 2624 + lane;
  const u16* hb = h3 + b * (NKPT * 64) + lane;
  float a0 = 0.f, a1 = 0.f;
  for (int l = 0; l < LSPIRAL; l++) {
    int J = ip[l];
    J = min(max(J, 0), NKPT - 1);
    const float hv = b2f(hb[J * 64]);
    a0 += hv * w0[l * 64];
    a1 += hv * w1[l * 64];
  }
#pragma unroll
  for (int off = 32; off > 0; off >>= 1) {
    a0 += __shfl_down(a0, off, 64);
    a1 += __shfl_down(a1, off, 64);
  }
  if (lane == 0) {
    out[r * 2 + 0] = a0 + b4[0];
    out[r * 2 + 1] = a1 + b4[1];
  }
}

extern "C" void kernel_launch(void* const* d_in, const int* in_sizes, int n_in,
                              void* d_out, int out_size, void* d_ws, size_t ws_size,
                              hipStream_t stream) {
  const float* x  = (const float*)d_in[0];
  const float* W0 = (const float*)d_in[1];
  const float* b0 = (const float*)d_in[2];
  const float* W1 = (const float*)d_in[3];
  const float* b1 = (const float*)d_in[4];
  const float* W2 = (const float*)d_in[5];
  const float* b2 = (const float*)d_in[6];
  const float* W3 = (const float*)d_in[7];
  const float* b3 = (const float*)d_in[8];
  const float* W4 = (const float*)d_in[9];
  const float* b4 = (const float*)d_in[10];
  const int* idx = (const int*)d_in[11];
  float* out = (float*)d_out;

  char* ws = (char*)d_ws;
  u16* hA  = (u16*)(ws);                  // 5,242,880 B  (h0, then h2)
  u16* hB  = (u16*)(ws + 5242880);        // 5,242,880 B  (h1, then h3)
  u16* xb  = (u16*)(ws + 10485760);       //   262,144 B
  u16* W1b = (u16*)(ws + 10747904);       // 5,373,952 B
  u16* W2b = (u16*)(ws + 16121856);       // 2,686,976 B
  u16* W3b = (u16*)(ws + 18808832);       //   671,744 B
  float* P = (float*)(ws + 19480576);     // 10,485,760 B -> end 29,966,336

  const bool full = ws_size >= (size_t)29966336;

  if (full) {
    // Zero L1's P up front; later epilogues re-zero for the next layer.
    zero_f32<<<2560, 256, 0, stream>>>(P, 655360);
    cvt_all<<<4393, 256, 0, stream>>>(x, W1, W2, W3, xb, W1b, W2b, W3b);

    // L0: M=128 N=20480 K=1024, direct out, fp32 B cvt at store (320 blocks)
    gemm_sp<128, 64, 0, 0, 0, 1, 1><<<dim3(1, 320, 1), 256, 0, stream>>>(
        xb, W0, idx, nullptr, hA, b0, 0, 20480, 1024, 16, 16);

    // L1: M=10240 N=256 K=10496, split 3 -> 480 blocks
    gemm_sp<128, 128, 1, 8, 1, 0, 16><<<dim3(80, 2, 3), 256, 0, stream>>>(
        hA, W1b, idx, P, nullptr, nullptr, 0, 256, 10496, 164, 55);
    epilogue_k<<<2560, 256, 0, stream>>>(P, b1, hB, 2621440, 256, 1, 1);

    // L2: N=128 K=10496, split 6 -> 480 blocks
    gemm_sp<128, 128, 1, 8, 1, 0, 16><<<dim3(80, 1, 6), 256, 0, stream>>>(
        hB, W2b, idx, P, nullptr, nullptr, 0, 128, 10496, 164, 28);
    epilogue_k<<<1280, 256, 0, stream>>>(P, b2, hA, 1310720, 128, 1, 1);

    // L3: N=64 K=5248, split 6 -> 480 blocks
    gemm_sp<128, 64, 1, 7, 1, 0, 16><<<dim3(80, 1, 12), 256, 0, stream>>>(
        hA, W3b, idx, P, nullptr, nullptr, 0, 64, 5248, 82, 7);
    epilogue_k<<<640, 256, 0, stream>>>(P, b3, hB, 655360, 64, 1, 0);
  } else {
    // Fallback (<= 10.5 MB ws): in-staging weight cvt, no split-K
    cvt_all<<<4393, 256, 0, stream>>>(x, x, x, x, hB, hB, hB, hB);  // only xb part used
    gemm_sp<128, 64, 0, 0, 0, 1, 1><<<dim3(1, 320, 1), 256, 0, stream>>>(
        hB, W0, idx, nullptr, hA, b0, 0, 20480, 1024, 16, 16);
    gemm_sp<128, 128, 1, 8, 0, 1, 44><<<dim3(80, 2, 1), 256, 0, stream>>>(
        hA, W1, idx, nullptr, hB, b1, 1, 256, 10496, 164, 164);
    gemm_sp<128, 128, 1, 8, 0, 1, 44><<<dim3(80, 1, 1), 256, 0, stream>>>(
        hB, W2, idx, nullptr, hA, b2, 1, 128, 10496, 164, 164);
    gemm_sp<128, 64, 1, 7, 0, 1, 44><<<dim3(80, 1, 1), 256, 0, stream>>>(
        hA, W3, idx, nullptr, hB, b3, 1, 64, 5248, 82, 82);
  }

  final_k<<<2560, 256, 0, stream>>>(hB, W4, b4, idx, out);
}